// Round 3
// baseline (301.149 us; speedup 1.0000x reference)
//
#include <hip/hip_runtime.h>

typedef float v2 __attribute__((ext_vector_type(2)));

// Fold 1/sqrt(3) (and log2(e) when raw exp2 is available) into staged Wq/bq.
#if __has_builtin(__builtin_amdgcn_exp2f)
#define QSCALE 0.8329441541679836f   // (1/sqrt(3)) * log2(e)
#define EXPFN(v) __builtin_amdgcn_exp2f(v)
#else
#define QSCALE 0.57735026918962576f  // 1/sqrt(3)
#define EXPFN(v) __expf(v)
#endif

// LDS layout, all float offsets.
// Q/K/V: [5 segs][3 pairs][16 floats]; seg stride 56 -> seg bases hit
// disjoint bank quads (0,24,16,8,0 mod 32; the one 2-way alias is free).
// Pair p holds head-interleaved rows (p, p+3):
//   [ (W[p][0],W[p+3][0]) ... (W[p][5],W[p+3][5]) (b[p],b[p+3]) pad ]
// Wo: [3 pairs][16], pair p = spatial rows (2p, 2p+1), bias in slot 12.
#define OFF_WQ 0
#define OFF_WK 280
#define OFF_WV 560
#define OFF_WO 840
#define LDS_FLOATS 888

template<int N>
__device__ __forceinline__ float rr(float x) {
    // row_ror within each 16-lane row: lane i <- lane (i+N)&15
    return __int_as_float(__builtin_amdgcn_mov_dpp(__float_as_int(x), 0x120 + N, 0xF, 0xF, true));
}
template<int N>
__device__ __forceinline__ v2 ror2(v2 a) { v2 r; r.x = rr<N>(a.x); r.y = rr<N>(a.y); return r; }
__device__ __forceinline__ v2 fma2(v2 a, v2 b, v2 c) { return __builtin_elementwise_fma(a, b, c); }
__device__ __forceinline__ v2 splat(float x) { v2 r; r.x = x; r.y = x; return r; }

__global__ __launch_bounds__(256) void attn_seg_kernel(
    const float* __restrict__ x,
    const float* __restrict__ Wq, const float* __restrict__ bq,
    const float* __restrict__ Wk, const float* __restrict__ bk,
    const float* __restrict__ Wv, const float* __restrict__ bv,
    const float* __restrict__ Wo, const float* __restrict__ bo,
    float* __restrict__ out, int nb)
{
    __shared__ __align__(16) float lds[LDS_FLOATS];
    const int t = threadIdx.x;

    // ---- stage weights (one-time) ----
    if (t < 180) {
        int sg = t / 36, rm = t - sg * 36, o = rm / 6, d = rm - o * 6;
        int dst = sg * 56 + (o % 3) * 16 + d * 2 + (o / 3);
        lds[OFF_WQ + dst] = Wq[t] * QSCALE;
        lds[OFF_WK + dst] = Wk[t];
        lds[OFF_WV + dst] = Wv[t];
    }
    if (t < 30) {
        int sg = t / 6, o = t - sg * 6;
        int dst = sg * 56 + (o % 3) * 16 + 12 + (o / 3);
        lds[OFF_WQ + dst] = bq[t] * QSCALE;
        lds[OFF_WK + dst] = bk[t];
        lds[OFF_WV + dst] = bv[t];
    }
    if (t < 36) {
        int o = t / 6, d = t - o * 6;
        lds[OFF_WO + (o >> 1) * 16 + d * 2 + (o & 1)] = Wo[t];
    }
    if (t < 6) {
        lds[OFF_WO + (t >> 1) * 16 + 12 + (t & 1)] = bo[t];
    }

    const int s = t & 15;          // sequence position
    const int r = t >> 4;          // batch row within block
    // SEG = [0, 1*5, 2*3, 3, 4*6]
    const int seg = (s == 0) ? 0 : (s < 6) ? 1 : (s < 9) ? 2 : (s == 9) ? 3 : 4;

    const int b0 = blockIdx.x * 32 + r;   // batch A
    const int b1 = b0 + 16;               // batch B
    const bool ok0 = b0 < nb, ok1 = b1 < nb;

    float xA[6] = {0,0,0,0,0,0}, xB[6] = {0,0,0,0,0,0};
    if (ok0) {
        const float* p = x + ((size_t)b0 * 16 + s) * 6;
        float2 a = *(const float2*)p, b = *(const float2*)(p + 2), c = *(const float2*)(p + 4);
        xA[0]=a.x; xA[1]=a.y; xA[2]=b.x; xA[3]=b.y; xA[4]=c.x; xA[5]=c.y;
    }
    if (ok1) {
        const float* p = x + ((size_t)b1 * 16 + s) * 6;
        float2 a = *(const float2*)p, b = *(const float2*)(p + 2), c = *(const float2*)(p + 4);
        xB[0]=a.x; xB[1]=a.y; xB[2]=b.x; xB[3]=b.y; xB[4]=c.x; xB[5]=c.y;
    }

    __syncthreads();   // weights visible

    // ---- projections: head-interleaved pairs, bias folded, wt reads shared ----
    v2 qA[3], kA[3], vA[3], qB[3], kB[3], vB[3];

#define PROJ(OFF, DA, DB) { \
    const float* Wb = &lds[(OFF) + seg * 56]; \
    _Pragma("unroll") \
    for (int p = 0; p < 3; p++) { \
        float4 wa = *(const float4*)(Wb + p * 16); \
        float4 wm = *(const float4*)(Wb + p * 16 + 4); \
        float4 wc = *(const float4*)(Wb + p * 16 + 8); \
        float2 bb = *(const float2*)(Wb + p * 16 + 12); \
        v2 w0; w0.x=wa.x; w0.y=wa.y;  v2 w1; w1.x=wa.z; w1.y=wa.w; \
        v2 w2; w2.x=wm.x; w2.y=wm.y;  v2 w3; w3.x=wm.z; w3.y=wm.w; \
        v2 w4; w4.x=wc.x; w4.y=wc.y;  v2 w5; w5.x=wc.z; w5.y=wc.w; \
        v2 aA; aA.x = bb.x; aA.y = bb.y;  v2 aB = aA; \
        aA = fma2(w0, splat(xA[0]), aA); aA = fma2(w1, splat(xA[1]), aA); \
        aA = fma2(w2, splat(xA[2]), aA); aA = fma2(w3, splat(xA[3]), aA); \
        aA = fma2(w4, splat(xA[4]), aA); aA = fma2(w5, splat(xA[5]), aA); \
        aB = fma2(w0, splat(xB[0]), aB); aB = fma2(w1, splat(xB[1]), aB); \
        aB = fma2(w2, splat(xB[2]), aB); aB = fma2(w3, splat(xB[3]), aB); \
        aB = fma2(w4, splat(xB[4]), aB); aB = fma2(w5, splat(xB[5]), aB); \
        DA[p] = aA; DB[p] = aB; \
    } }

    PROJ(OFF_WQ, qA, qB)
    PROJ(OFF_WK, kA, kB)
    PROJ(OFF_WV, vA, vB)
#undef PROJ

    // ---- fused score -> exp -> sum -> PV, DPP row-rotate, no max-subtract ----
    v2 sumA, sumB, cA[3], cB[3];
    {
        v2 sa = fma2(qA[0], kA[0], fma2(qA[1], kA[1], qA[2] * kA[2]));
        v2 pa; pa.x = EXPFN(sa.x); pa.y = EXPFN(sa.y);
        sumA = pa; cA[0] = pa * vA[0]; cA[1] = pa * vA[1]; cA[2] = pa * vA[2];
        v2 sb = fma2(qB[0], kB[0], fma2(qB[1], kB[1], qB[2] * kB[2]));
        v2 pb; pb.x = EXPFN(sb.x); pb.y = EXPFN(sb.y);
        sumB = pb; cB[0] = pb * vB[0]; cB[1] = pb * vB[1]; cB[2] = pb * vB[2];
    }

#define STEP(J) { \
    v2 ka0 = ror2<J>(kA[0]), ka1 = ror2<J>(kA[1]), ka2 = ror2<J>(kA[2]); \
    v2 sa = fma2(qA[0], ka0, fma2(qA[1], ka1, qA[2] * ka2)); \
    v2 pa; pa.x = EXPFN(sa.x); pa.y = EXPFN(sa.y); \
    sumA += pa; \
    v2 va0 = ror2<J>(vA[0]), va1 = ror2<J>(vA[1]), va2 = ror2<J>(vA[2]); \
    cA[0] = fma2(pa, va0, cA[0]); cA[1] = fma2(pa, va1, cA[1]); cA[2] = fma2(pa, va2, cA[2]); \
    v2 kb0 = ror2<J>(kB[0]), kb1 = ror2<J>(kB[1]), kb2 = ror2<J>(kB[2]); \
    v2 sb = fma2(qB[0], kb0, fma2(qB[1], kb1, qB[2] * kb2)); \
    v2 pb; pb.x = EXPFN(sb.x); pb.y = EXPFN(sb.y); \
    sumB += pb; \
    v2 vb0 = ror2<J>(vB[0]), vb1 = ror2<J>(vB[1]), vb2 = ror2<J>(vB[2]); \
    cB[0] = fma2(pb, vb0, cB[0]); cB[1] = fma2(pb, vb1, cB[1]); cB[2] = fma2(pb, vb2, cB[2]); }

    STEP(1)  STEP(2)  STEP(3)  STEP(4)  STEP(5)
    STEP(6)  STEP(7)  STEP(8)  STEP(9)  STEP(10)
    STEP(11) STEP(12) STEP(13) STEP(14) STEP(15)
#undef STEP

    // ---- normalize: pair = (1/sum_head0, 1/sum_head1) ----
    v2 invA; invA.x = __builtin_amdgcn_rcpf(sumA.x); invA.y = __builtin_amdgcn_rcpf(sumA.y);
    v2 invB; invB.x = __builtin_amdgcn_rcpf(sumB.x); invB.y = __builtin_amdgcn_rcpf(sumB.y);
    cA[0] *= invA; cA[1] *= invA; cA[2] *= invA;
    cB[0] *= invB; cB[1] *= invB; cB[2] *= invB;

    const float ctxA[6] = {cA[0].x, cA[1].x, cA[2].x, cA[0].y, cA[1].y, cA[2].y};
    const float ctxB[6] = {cB[0].x, cB[1].x, cB[2].x, cB[0].y, cB[1].y, cB[2].y};

    // ---- output projection (pairs over spatial rows) + store ----
    float* oA = out + ((size_t)b0 * 16 + s) * 6;
    float* oB = out + ((size_t)b1 * 16 + s) * 6;
    const float* Wb = &lds[OFF_WO];
    #pragma unroll
    for (int p = 0; p < 3; p++) {
        float4 wa = *(const float4*)(Wb + p * 16);
        float4 wm = *(const float4*)(Wb + p * 16 + 4);
        float4 wc = *(const float4*)(Wb + p * 16 + 8);
        float2 bb = *(const float2*)(Wb + p * 16 + 12);
        v2 w0; w0.x=wa.x; w0.y=wa.y;  v2 w1; w1.x=wa.z; w1.y=wa.w;
        v2 w2; w2.x=wm.x; w2.y=wm.y;  v2 w3; w3.x=wm.z; w3.y=wm.w;
        v2 w4; w4.x=wc.x; w4.y=wc.y;  v2 w5; w5.x=wc.z; w5.y=wc.w;
        v2 aA; aA.x = bb.x; aA.y = bb.y;  v2 aB = aA;
        aA = fma2(w0, splat(ctxA[0]), aA); aA = fma2(w1, splat(ctxA[1]), aA);
        aA = fma2(w2, splat(ctxA[2]), aA); aA = fma2(w3, splat(ctxA[3]), aA);
        aA = fma2(w4, splat(ctxA[4]), aA); aA = fma2(w5, splat(ctxA[5]), aA);
        aB = fma2(w0, splat(ctxB[0]), aB); aB = fma2(w1, splat(ctxB[1]), aB);
        aB = fma2(w2, splat(ctxB[2]), aB); aB = fma2(w3, splat(ctxB[3]), aB);
        aB = fma2(w4, splat(ctxB[4]), aB); aB = fma2(w5, splat(ctxB[5]), aB);
        if (ok0) *(float2*)(oA + 2 * p) = make_float2(aA.x, aA.y);
        if (ok1) *(float2*)(oB + 2 * p) = make_float2(aB.x, aB.y);
    }
}

extern "C" void kernel_launch(void* const* d_in, const int* in_sizes, int n_in,
                              void* d_out, int out_size, void* d_ws, size_t ws_size,
                              hipStream_t stream) {
    const float* x  = (const float*)d_in[0];
    const float* Wq = (const float*)d_in[1];
    const float* bq = (const float*)d_in[2];
    const float* Wk = (const float*)d_in[3];
    const float* bk = (const float*)d_in[4];
    const float* Wv = (const float*)d_in[5];
    const float* bv = (const float*)d_in[6];
    const float* Wo = (const float*)d_in[7];
    const float* bo = (const float*)d_in[8];
    float* out = (float*)d_out;

    const int nb   = in_sizes[0] / 96;      // batch elements (16 pos x 6 dim)
    const int grid = (nb + 31) / 32;        // 32 batch elems / block (2 per thread)
    attn_seg_kernel<<<grid, 256, 0, stream>>>(x, Wq, bq, Wk, bk, Wv, bv, Wo, bo, out, nb);
}